// Round 5
// baseline (504.753 us; speedup 1.0000x reference)
//
#include <hip/hip_runtime.h>
#include <hip/hip_bf16.h>
#include <cmath>

// Problem constants
#define BB 64
#define TT 2048
#define EE 1024
#define DD 1024
#define FAN 2048

typedef __attribute__((ext_vector_type(8))) short bhalf8;
typedef __attribute__((ext_vector_type(4))) float fvec4;

// ws layout (bytes)
#define OFF_WE   0u          // 2 MB  : We bf16, pre-swizzled [ec][eo][d][8]
#define OFF_C    2097152u    // 256 KB: c[b,d] = dec·Wd + bias
#define OFF_S    2359296u    // 512 KB: scores[b,t]
#define OFF_A    2883584u    // 512 KB: alpha[b,t]
#define OFF_P    3407872u    // 4 MB  : context partials [16][64][1024]

__device__ __forceinline__ short f2bf(float f) {
    unsigned int u = __float_as_uint(f);
    u += 0x7FFFu + ((u >> 16) & 1u);   // round-to-nearest-even
    return (short)(u >> 16);
}

__device__ __forceinline__ bhalf8 cvt8(float4 a, float4 b) {
    bhalf8 h;
    h[0] = f2bf(a.x); h[1] = f2bf(a.y); h[2] = f2bf(a.z); h[3] = f2bf(a.w);
    h[4] = f2bf(b.x); h[5] = f2bf(b.y); h[6] = f2bf(b.z); h[7] = f2bf(b.w);
    return h;
}

__device__ __forceinline__ float fast_tanhf(float x) {
    float ax = __builtin_fabsf(x);
    float e  = __expf(-2.0f * ax);
    float r  = (1.0f - e) * __builtin_amdgcn_rcpf(1.0f + e);
    return __builtin_copysignf(r, x);
}

// LDS-only barrier: order ds ops, do NOT drain vmcnt (global loads stay in
// flight across it — __syncthreads would force vmcnt(0)).
__device__ __forceinline__ void lds_barrier() {
    asm volatile("s_waitcnt lgkmcnt(0)" ::: "memory");
    __builtin_amdgcn_s_barrier();
}

// ---------------- kernel 0a: convert We (f32) -> pre-swizzled bf16 image ----
// image layout per 32-wide e-chunk ec: byte = ec*65536 + eo*16384 + d*16 + r*2
__global__ void prep_we_k(const float* __restrict__ W, short* __restrict__ wsWe) {
    int g  = blockIdx.x * 256 + threadIdx.x;   // 0..131071
    int ec = g >> 12;          // 0..31
    int eo = (g >> 10) & 3;    // 0..3
    int d  = g & 1023;
    const float* src = W + (size_t)d * FAN + ec * 32 + eo * 8;
    float4 f0 = *(const float4*)src;
    float4 f1 = *(const float4*)(src + 4);
    *(bhalf8*)((char*)wsWe + (size_t)ec * 65536 + eo * 16384 + d * 16) = cvt8(f0, f1);
}

// ---------------- kernel 0b: c[b,d] = dec[b,:]·Wd[d,:] + bias[d] ------------
__global__ void prep_c_k(const float* __restrict__ W, const float* __restrict__ bias,
                         const float* __restrict__ dec, float* __restrict__ cbuf) {
    int wg   = blockIdx.x * 4 + (threadIdx.x >> 6);  // 0..65535
    int lane = threadIdx.x & 63;
    int b = wg >> 10, d = wg & 1023;
    const float* wrow = W + (size_t)d * FAN + EE;    // Wd part
    const float* drow = dec + b * DD;
    float p = 0.f;
#pragma unroll
    for (int i = 0; i < 16; ++i)
        p += wrow[i * 64 + lane] * drow[i * 64 + lane];
#pragma unroll
    for (int off = 1; off < 64; off <<= 1)
        p += __shfl_xor(p, off);
    if (lane == 0) cbuf[b * DD + d] = p + bias[d];
}

// ---------------- kernel 1: scores[b,t] = v · tanh(enc·We^T + c) ------------
// 512 thr (8 waves), tile 64 t x 1024 d, wave w owns d-slice [w*128, +128).
// BK=64 double-buffered A chunks in LDS (XOR-swizzled, 0 conflicts), depth-2
// register prefetch of the fp32 A chunk, half-step-ahead B register
// double-buffer from the L2-resident pre-swizzled We image. K-loop barrier is
// lgkmcnt-only (raw s_barrier) so global loads pipeline across steps.
__global__ __launch_bounds__(512, 2)
void scores_k(const float* __restrict__ enc, const short* __restrict__ wsWe,
              const float* __restrict__ cbuf, const float* __restrict__ vw,
              float* __restrict__ scores) {
    __shared__ short sA[2][8][64][8];   // 16 KB: [buf][eo][t^eo][8e]
    __shared__ float sRed[8][64];       // 2 KB

    const int tid  = threadIdx.x;
    const int w    = tid >> 6;
    const int lane = tid & 63;
    const int lrow = lane >> 4;   // 0..3
    const int lcol = lane & 15;
    const int b  = blockIdx.y;
    const int t0 = blockIdx.x * 64;

    // staging: thread -> (t row st, e-octet seo); 256B-contiguous global reads
    const int st  = tid >> 3;     // 0..63
    const int seo = tid & 7;      // 0..7
    const float* gsrc = enc + ((size_t)(b * TT + t0 + st)) * EE + seo * 8;

    fvec4 acc[4][8];
#pragma unroll
    for (int m = 0; m < 4; ++m)
#pragma unroll
        for (int n = 0; n < 8; ++n)
            acc[m][n] = (fvec4){0.f, 0.f, 0.f, 0.f};

    // per-lane B base (eo=lrow, d=w*128+lcol)
    const char* Bbase = (const char*)wsWe + lrow * 16384 + (w * 128 + lcol) * 16;

    bhalf8 bf0[8], bf1[8];
    // ---- prologue: chunk0 -> setA, chunk1 -> setB, B frags ks=0, write chunk0
    float4 pA0 = *(const float4*)(gsrc);
    float4 pA1 = *(const float4*)(gsrc + 4);
    float4 pB0 = *(const float4*)(gsrc + 64);
    float4 pB1 = *(const float4*)(gsrc + 68);
#pragma unroll
    for (int n = 0; n < 8; ++n)
        bf0[n] = *(const bhalf8*)(Bbase + n * 256);
    *(bhalf8*)&sA[0][seo][st ^ seo][0] = cvt8(pA0, pA1);
    lds_barrier();

#pragma unroll
    for (int i = 0; i < 15; ++i) {
        const int buf = i & 1, nbuf = buf ^ 1;
        // (1) A chunk i+2 global loads into the freed register set (set i&1)
        if (i + 2 < 16) {
            if ((i & 1) == 0) {
                pA0 = *(const float4*)(gsrc + (i + 2) * 64);
                pA1 = *(const float4*)(gsrc + (i + 2) * 64 + 4);
            } else {
                pB0 = *(const float4*)(gsrc + (i + 2) * 64);
                pB1 = *(const float4*)(gsrc + (i + 2) * 64 + 4);
            }
        }
        // (2) B frags ks=2i+1 (consumed after kk0 MFMAs)
#pragma unroll
        for (int n = 0; n < 8; ++n)
            bf1[n] = *(const bhalf8*)(Bbase + (size_t)(2 * i + 1) * 65536 + n * 256);
        // (3) kk=0: af reads + MFMA
        {
            bhalf8 af[4];
#pragma unroll
            for (int m = 0; m < 4; ++m) {
                int t = m * 16 + lcol;
                af[m] = *(const bhalf8*)&sA[buf][lrow][t ^ lrow][0];
            }
#pragma unroll
            for (int n = 0; n < 8; ++n)
#pragma unroll
                for (int m = 0; m < 4; ++m)
                    acc[m][n] = __builtin_amdgcn_mfma_f32_16x16x32_bf16(af[m], bf0[n], acc[m][n], 0, 0, 0);
        }
        // (4) B frags ks=2i+2 for next step (covered by kk1 + barrier + (1))
#pragma unroll
        for (int n = 0; n < 8; ++n)
            bf0[n] = *(const bhalf8*)(Bbase + (size_t)(2 * i + 2) * 65536 + n * 256);
        // (5) kk=1: af reads + MFMA
        {
            bhalf8 af[4];
#pragma unroll
            for (int m = 0; m < 4; ++m) {
                int t = m * 16 + lcol;
                int eo = 4 + lrow;
                af[m] = *(const bhalf8*)&sA[buf][eo][t ^ eo][0];
            }
#pragma unroll
            for (int n = 0; n < 8; ++n)
#pragma unroll
                for (int m = 0; m < 4; ++m)
                    acc[m][n] = __builtin_amdgcn_mfma_f32_16x16x32_bf16(af[m], bf1[n], acc[m][n], 0, 0, 0);
        }
        // (6) cvt + swizzled write of chunk i+1 (loaded at step i-1: ~2 steps cover)
        {
            bhalf8 h = ((i & 1) == 0) ? cvt8(pB0, pB1) : cvt8(pA0, pA1);
            *(bhalf8*)&sA[nbuf][seo][st ^ seo][0] = h;
        }
        lds_barrier();
    }
    // final step i=15 (buf=1, no staging, no barrier)
    {
#pragma unroll
        for (int n = 0; n < 8; ++n)
            bf1[n] = *(const bhalf8*)(Bbase + (size_t)31 * 65536 + n * 256);
        bhalf8 af[4];
#pragma unroll
        for (int m = 0; m < 4; ++m) {
            int t = m * 16 + lcol;
            af[m] = *(const bhalf8*)&sA[1][lrow][t ^ lrow][0];
        }
#pragma unroll
        for (int n = 0; n < 8; ++n)
#pragma unroll
            for (int m = 0; m < 4; ++m)
                acc[m][n] = __builtin_amdgcn_mfma_f32_16x16x32_bf16(af[m], bf0[n], acc[m][n], 0, 0, 0);
#pragma unroll
        for (int m = 0; m < 4; ++m) {
            int t = m * 16 + lcol;
            int eo = 4 + lrow;
            af[m] = *(const bhalf8*)&sA[1][eo][t ^ eo][0];
        }
#pragma unroll
        for (int n = 0; n < 8; ++n)
#pragma unroll
            for (int m = 0; m < 4; ++m)
                acc[m][n] = __builtin_amdgcn_mfma_f32_16x16x32_bf16(af[m], bf1[n], acc[m][n], 0, 0, 0);
    }

    float cv[8], vv[8];
#pragma unroll
    for (int n = 0; n < 8; ++n) {
        int d = w * 128 + n * 16 + lcol;
        cv[n] = cbuf[b * DD + d];
        vv[n] = vw[d];
    }

    // epilogue: tanh + v-dot, reduce over d
#pragma unroll
    for (int m = 0; m < 4; ++m) {
#pragma unroll
        for (int j = 0; j < 4; ++j) {
            float p = 0.f;
#pragma unroll
            for (int n = 0; n < 8; ++n)
                p += vv[n] * fast_tanhf(acc[m][n][j] + cv[n]);
            p += __shfl_xor(p, 1); p += __shfl_xor(p, 2);
            p += __shfl_xor(p, 4); p += __shfl_xor(p, 8);
            if (lcol == 0) sRed[w][m * 16 + lrow * 4 + j] = p;
        }
    }
    __syncthreads();
    if (tid < 64) {
        float s = 0.f;
#pragma unroll
        for (int w2 = 0; w2 < 8; ++w2) s += sRed[w2][tid];
        scores[b * TT + t0 + tid] = s;
    }
}

// ---------------- kernel 2: softmax over t per batch ------------------------
__global__ void softmax_k(const float* __restrict__ scores, float* __restrict__ alpha) {
    int b = blockIdx.x, tid = threadIdx.x;
    float s[8];
    float m = -1e30f;
#pragma unroll
    for (int i = 0; i < 8; ++i) {
        s[i] = scores[b * TT + i * 256 + tid];
        m = fmaxf(m, s[i]);
    }
#pragma unroll
    for (int off = 1; off < 64; off <<= 1) m = fmaxf(m, __shfl_xor(m, off));
    __shared__ float red[4], red2[4];
    if ((tid & 63) == 0) red[tid >> 6] = m;
    __syncthreads();
    m = fmaxf(fmaxf(red[0], red[1]), fmaxf(red[2], red[3]));
    float sum = 0.f;
#pragma unroll
    for (int i = 0; i < 8; ++i) { s[i] = expf(s[i] - m); sum += s[i]; }
#pragma unroll
    for (int off = 1; off < 64; off <<= 1) sum += __shfl_xor(sum, off);
    if ((tid & 63) == 0) red2[tid >> 6] = sum;
    __syncthreads();
    sum = red2[0] + red2[1] + red2[2] + red2[3];
    float inv = 1.0f / sum;
#pragma unroll
    for (int i = 0; i < 8; ++i) alpha[b * TT + i * 256 + tid] = s[i] * inv;
}

// ---------------- kernel 3: context partials over t-slices ------------------
// grid (16 t-slices, 64 b), 256 thr, each thread owns 4 consecutive e
__global__ void ctx_k(const float* __restrict__ enc, const float* __restrict__ alpha,
                      float* __restrict__ part) {
    int ts = blockIdx.x, b = blockIdx.y, tid = threadIdx.x;
    __shared__ float sAl[128];
    if (tid < 128) sAl[tid] = alpha[b * TT + ts * 128 + tid];
    __syncthreads();
    float4 acc = {0.f, 0.f, 0.f, 0.f};
    const float* base = enc + ((size_t)b * TT + ts * 128) * EE + tid * 4;
#pragma unroll 8
    for (int i = 0; i < 128; ++i) {
        float4 v = *(const float4*)(base + (size_t)i * EE);
        float a = sAl[i];
        acc.x += a * v.x; acc.y += a * v.y; acc.z += a * v.z; acc.w += a * v.w;
    }
    *(float4*)&part[(size_t)(ts * 64 + b) * EE + tid * 4] = acc;
}

// ---------------- kernel 4: combine partials --------------------------------
__global__ void comb_k(const float* __restrict__ part, float* __restrict__ out) {
    int g = blockIdx.x * 256 + threadIdx.x;   // 0..65535
    float s = 0.f;
#pragma unroll
    for (int ts = 0; ts < 16; ++ts) s += part[(size_t)ts * 65536 + g];
    out[g] = s;
}

extern "C" void kernel_launch(void* const* d_in, const int* in_sizes, int n_in,
                              void* d_out, int out_size, void* d_ws, size_t ws_size,
                              hipStream_t stream) {
    const float* enc  = (const float*)d_in[0];
    const float* dec  = (const float*)d_in[1];
    const float* W    = (const float*)d_in[2];
    const float* bias = (const float*)d_in[3];
    const float* vw   = (const float*)d_in[4];
    float* out = (float*)d_out;

    char* ws = (char*)d_ws;
    short* wsWe   = (short*)(ws + OFF_WE);
    float* cbuf   = (float*)(ws + OFF_C);
    float* scores = (float*)(ws + OFF_S);
    float* alpha  = (float*)(ws + OFF_A);
    float* part   = (float*)(ws + OFF_P);

    prep_we_k<<<512, 256, 0, stream>>>(W, wsWe);
    prep_c_k<<<16384, 256, 0, stream>>>(W, bias, dec, cbuf);
    scores_k<<<dim3(32, 64), 512, 0, stream>>>(enc, wsWe, cbuf, vw, scores);
    softmax_k<<<64, 256, 0, stream>>>(scores, alpha);
    ctx_k<<<dim3(16, 64), 256, 0, stream>>>(enc, alpha, part);
    comb_k<<<256, 256, 0, stream>>>(part, out);
}